// Round 6
// baseline (439.162 us; speedup 1.0000x reference)
//
#include <hip/hip_runtime.h>

#define NNODES 100000
#define NEDGES 1600000

typedef short bhalf8 __attribute__((ext_vector_type(8)));   // 8 bf16 bit patterns
typedef float f32x4 __attribute__((ext_vector_type(4)));

__device__ __forceinline__ unsigned fbits(float x){ union{float f;unsigned u;}c; c.f=x; return c.u; }
__device__ __forceinline__ float bcast(unsigned u){ union{float f;unsigned u;}c; c.u=u; return c.f; }
// round-to-nearest-even bf16 (top 16 bits of fp32)
__device__ __forceinline__ unsigned short rtn16(float x){
    unsigned u = fbits(x);
    return (unsigned short)((u + 0x7FFFu + ((u >> 16) & 1u)) >> 16);
}

// ---------------- edge dtype detect: int64 vs int32 ----------------
__global__ void detect_kernel(const int* __restrict__ ei, int* __restrict__ flag) {
    int t = threadIdx.x;                 // 0..63
    int v = ei[2 * t + 1];
    unsigned long long nz = __ballot(v != 0);
    if (t == 0) flag[0] = (nz == 0ULL) ? 1 : 0;   // 1 => int64 layout
}

// ---------------- pack edges to int32 ----------
__global__ void prep_edges(const int* __restrict__ ei, const int* __restrict__ flag,
                           int* __restrict__ src32, int* __restrict__ dst32) {
    int is64 = flag[0];
    for (int e = blockIdx.x * blockDim.x + threadIdx.x; e < NEDGES;
         e += gridDim.x * blockDim.x) {
        src32[e] = is64 ? ei[2 * e] : ei[e];
        dst32[e] = is64 ? ei[2 * (NEDGES + e)] : ei[NEDGES + e];
    }
}

// ---------------- CSR build ----------------
__global__ void hist_kernel(const int* __restrict__ dst32, int* __restrict__ deg) {
    for (int e = blockIdx.x * blockDim.x + threadIdx.x; e < NEDGES;
         e += gridDim.x * blockDim.x) {
        atomicAdd(&deg[dst32[e]], 1);
    }
}

__global__ void scan_bsum(const int* __restrict__ deg, int* __restrict__ bsums) {
    int b = blockIdx.x, t = threadIdx.x;
    long i0 = (long)b * 1024 + (long)t * 4;
    int v0 = 0, v1 = 0, v2 = 0, v3 = 0;
    if (i0 + 3 < NNODES) {
        int4 q = *(const int4*)&deg[i0];
        v0 = q.x; v1 = q.y; v2 = q.z; v3 = q.w;
    } else {
        if (i0 + 0 < NNODES) v0 = deg[i0 + 0];
        if (i0 + 1 < NNODES) v1 = deg[i0 + 1];
        if (i0 + 2 < NNODES) v2 = deg[i0 + 2];
        if (i0 + 3 < NNODES) v3 = deg[i0 + 3];
    }
    int s = v0 + v1 + v2 + v3;
    for (int off = 32; off > 0; off >>= 1) s += __shfl_down(s, off);
    __shared__ int ws[4];
    if ((t & 63) == 0) ws[t >> 6] = s;
    __syncthreads();
    if (t == 0) bsums[b] = ws[0] + ws[1] + ws[2] + ws[3];
}

__global__ void scan_partials(int* __restrict__ bsums, int nb) {
    __shared__ int sm[128];
    int t = threadIdx.x;
    int v = (t < nb) ? bsums[t] : 0;
    int run = v;
    sm[t] = run;
    __syncthreads();
    for (int off = 1; off < 128; off <<= 1) {
        int other = (t >= off) ? sm[t - off] : 0;
        __syncthreads();
        run += other;
        sm[t] = run;
        __syncthreads();
    }
    if (t < nb) bsums[t] = run - v;      // exclusive
}

__global__ void scan_write(const int* __restrict__ deg, const int* __restrict__ bsums,
                           int* __restrict__ offs) {
    int b = blockIdx.x, t = threadIdx.x;
    long i0 = (long)b * 1024 + (long)t * 4;
    int v0 = 0, v1 = 0, v2 = 0, v3 = 0;
    if (i0 + 3 < NNODES) {
        int4 q = *(const int4*)&deg[i0];
        v0 = q.x; v1 = q.y; v2 = q.z; v3 = q.w;
    } else {
        if (i0 + 0 < NNODES) v0 = deg[i0 + 0];
        if (i0 + 1 < NNODES) v1 = deg[i0 + 1];
        if (i0 + 2 < NNODES) v2 = deg[i0 + 2];
        if (i0 + 3 < NNODES) v3 = deg[i0 + 3];
    }
    int tot = v0 + v1 + v2 + v3;
    __shared__ int sm[256];
    int run = tot;
    sm[t] = run;
    __syncthreads();
    for (int off = 1; off < 256; off <<= 1) {
        int other = (t >= off) ? sm[t - off] : 0;
        __syncthreads();
        run += other;
        sm[t] = run;
        __syncthreads();
    }
    int excl = run - tot + bsums[b];
    if (i0 + 0 < NNODES) offs[i0 + 0] = excl;
    if (i0 + 1 < NNODES) offs[i0 + 1] = excl + v0;
    if (i0 + 2 < NNODES) offs[i0 + 2] = excl + v0 + v1;
    if (i0 + 3 < NNODES) offs[i0 + 3] = excl + v0 + v1 + v2;
    if (b == 0 && t == 0) offs[NNODES] = NEDGES;
}

__global__ void copy_kernel(const int* __restrict__ src, int* __restrict__ dst) {
    int i = blockIdx.x * blockDim.x + threadIdx.x;
    if (i < NNODES) dst[i] = src[i];
}

// 8 dst-range cohorts (XCD-aligned) to merge csr line writes in one L2.
__global__ void scatter8(const int* __restrict__ src32, const int* __restrict__ dst32,
                         int* __restrict__ cursor, int* __restrict__ csr) {
    const int cohort = blockIdx.x & 7;
    const int lo = cohort * 12500, hi = lo + 12500;
    const int nb = gridDim.x >> 3;
    for (int e = (blockIdx.x >> 3) * blockDim.x + threadIdx.x; e < NEDGES;
         e += nb * blockDim.x) {
        int d = dst32[e];
        if (d >= lo && d < hi) {
            int pos = atomicAdd(&cursor[d], 1);
            csr[pos] = src32[e];
        }
    }
}

// ---------------- weight prep: fp32 -> bf16 3-way split (RTN) in B-frag order
template <int K, int NL, int NTOT>
__global__ void prep_w(const float* __restrict__ wl, const float* __restrict__ wr,
                       unsigned short* __restrict__ Bh, unsigned short* __restrict__ Bm,
                       unsigned short* __restrict__ Bl) {
    constexpr int NCT = NTOT / 16;
    constexpr int TOT = (K / 32) * NCT * 512;
    for (int idx = blockIdx.x * blockDim.x + threadIdx.x; idx < TOT;
         idx += gridDim.x * blockDim.x) {
        int e = idx & 7, l = (idx >> 3) & 63, rest = idx >> 9;
        int ct = rest % NCT, kc = rest / NCT;
        int k = kc * 32 + (l >> 4) * 8 + e;
        int j = ct * 16 + (l & 15);
        float v = (j < NL) ? wl[k * NL + j] : wr[k * NL + (j - NL)];
        unsigned short h = rtn16(v);
        float r1 = v - bcast((unsigned)h << 16);    // exact
        unsigned short mdl = rtn16(r1);
        float r2 = r1 - bcast((unsigned)mdl << 16); // exact
        Bh[idx] = h;
        Bm[idx] = mdl;
        Bl[idx] = rtn16(r2);
    }
}

// ---------------- MFMA dual GEMM: Z = h @ [wl|wr], fp32-exact via 3-way split
// a = ah+am+al (each bf16, RTN, residual <= 2^-24|a|); 6 products cover all
// terms >= 2^-24|ab|: hh, hm, mh, hl, mm, lh.
template <int K, int NL, int NTOT>
__global__ __launch_bounds__(256) void gemm_mfma(
    const float* __restrict__ h, const unsigned short* __restrict__ Bh,
    const unsigned short* __restrict__ Bm, const unsigned short* __restrict__ Bl,
    const float* __restrict__ bias,
    float* __restrict__ zl, float* __restrict__ zr, int nrows) {
    constexpr int NCT = NTOT / 16;
    constexpr int NKC = K / 32;
    int t = threadIdx.x;
    int l = t & 63, w = t >> 6;
    int rb = blockIdx.x * 64 + w * 16;
    int arow = rb + (l & 15);
    int kg = l >> 4;
    f32x4 acc[NCT];
#pragma unroll
    for (int ct = 0; ct < NCT; ++ct) acc[ct] = (f32x4){0.f, 0.f, 0.f, 0.f};
    const bool aok = (arow < nrows);
    const float* hrow = h + (long)arow * K + kg * 8;
#pragma unroll
    for (int kc = 0; kc < NKC; ++kc) {
        float4 a0 = make_float4(0.f, 0.f, 0.f, 0.f), a1 = a0;
        if (aok) {
            a0 = *(const float4*)(hrow + kc * 32);
            a1 = *(const float4*)(hrow + kc * 32 + 4);
        }
        float av[8] = {a0.x, a0.y, a0.z, a0.w, a1.x, a1.y, a1.z, a1.w};
        bhalf8 ah, am, al;
#pragma unroll
        for (int e = 0; e < 8; ++e) {
            unsigned short hh = rtn16(av[e]);
            float r1 = av[e] - bcast((unsigned)hh << 16);
            unsigned short mm = rtn16(r1);
            float r2 = r1 - bcast((unsigned)mm << 16);
            ah[e] = (short)hh;
            am[e] = (short)mm;
            al[e] = (short)rtn16(r2);
        }
        const unsigned short* hp = Bh + (size_t)(kc * NCT) * 512 + l * 8;
        const unsigned short* mp = Bm + (size_t)(kc * NCT) * 512 + l * 8;
        const unsigned short* lp = Bl + (size_t)(kc * NCT) * 512 + l * 8;
#pragma unroll
        for (int ct = 0; ct < NCT; ++ct) {
            bhalf8 bh = *(const bhalf8*)(hp + ct * 512);
            bhalf8 bm = *(const bhalf8*)(mp + ct * 512);
            bhalf8 bl = *(const bhalf8*)(lp + ct * 512);
            acc[ct] = __builtin_amdgcn_mfma_f32_16x16x32_bf16(ah, bh, acc[ct], 0, 0, 0);
            acc[ct] = __builtin_amdgcn_mfma_f32_16x16x32_bf16(ah, bm, acc[ct], 0, 0, 0);
            acc[ct] = __builtin_amdgcn_mfma_f32_16x16x32_bf16(am, bh, acc[ct], 0, 0, 0);
            acc[ct] = __builtin_amdgcn_mfma_f32_16x16x32_bf16(ah, bl, acc[ct], 0, 0, 0);
            acc[ct] = __builtin_amdgcn_mfma_f32_16x16x32_bf16(am, bm, acc[ct], 0, 0, 0);
            acc[ct] = __builtin_amdgcn_mfma_f32_16x16x32_bf16(al, bh, acc[ct], 0, 0, 0);
        }
    }
    // D: col = l&15, row = rb + (l>>4)*4 + r   [m89-verified]
    int orow0 = rb + kg * 4;
#pragma unroll
    for (int ct = 0; ct < NCT; ++ct) {
        int j = ct * 16 + (l & 15);
        bool isl = (j < NL);
        int cc = isl ? j : j - NL;
        float bj = isl ? 0.f : bias[cc];
        float* __restrict__ dp = isl ? zl : zr;
#pragma unroll
        for (int r = 0; r < 4; ++r) {
            int orow = orow0 + r;
            if (orow < nrows) dp[(long)orow * NL + cc] = acc[ct][r] + bj;
        }
    }
}

// ---------------- aggregate + combine + epilogue ----------------
// float2 lanes: lanes 0-31 gather even edge, 32-63 odd edge; 8 loads in flight.
// MODE: 0 = relu, 1 = bn+relu, 2 = bn
template <int NOUT, int MODE>
__global__ __launch_bounds__(256) void combine_kernel(
    const float* __restrict__ zl, const float* __restrict__ zr,
    const int* __restrict__ offs, const int* __restrict__ csr,
    const float* __restrict__ g, const float* __restrict__ bb,
    const float* __restrict__ m, const float* __restrict__ v,
    float* __restrict__ out) {
    int wid  = (blockIdx.x * blockDim.x + threadIdx.x) >> 6;
    int lane = threadIdx.x & 63;
    if (wid >= NNODES) return;
    int s0 = offs[wid], s1 = offs[wid + 1];
    int half = lane >> 5;
    int li2  = (lane & 31) * 2;
    const bool cok = (li2 < NOUT);
    float ax = 0.f, ay = 0.f;
    for (int base = s0; base < s1; base += 64) {
        int c = min(64, s1 - base);
        int sv = (base + lane < s1) ? csr[base + lane] : 0;
        for (int p0 = 0; p0 < c; p0 += 16) {       // 16 edges / chunk
            float vx[8], vy[8];
            bool okk[8];
#pragma unroll
            for (int j = 0; j < 8; ++j) {
                int eidx = p0 + 2 * j + half;
                bool ok = eidx < c;
                okk[j] = ok;
                int srow = ok ? __shfl(sv, eidx) : 0;   // row 0: cache-hot dummy
                float2 vv = make_float2(0.f, 0.f);
                if (cok) vv = *(const float2*)&zl[(long)srow * NOUT + li2];
                vx[j] = vv.x; vy[j] = vv.y;
            }
#pragma unroll
            for (int j = 0; j < 8; ++j) {
                if (okk[j]) { ax += vx[j]; ay += vy[j]; }
            }
        }
    }
    // cross-half reduce: even-edge partial (lanes<32) + odd-edge partial
    ax += __shfl_xor(ax, 32);
    ay += __shfl_xor(ay, 32);
    if (half != 0 || !cok) return;
    float invd = 1.f / fmaxf((float)(s1 - s0), 1.f);
    float2 zrv = *(const float2*)&zr[(long)wid * NOUT + li2];
    float r0 = ax * invd + zrv.x;
    float r1 = ay * invd + zrv.y;
    if (MODE == 1 || MODE == 2) {
        float sc0 = g[li2]     * rsqrtf(v[li2]     + 1e-5f);
        float sc1 = g[li2 + 1] * rsqrtf(v[li2 + 1] + 1e-5f);
        r0 = (r0 - m[li2])     * sc0 + bb[li2];
        r1 = (r1 - m[li2 + 1]) * sc1 + bb[li2 + 1];
    }
    if (MODE == 0 || MODE == 1) { r0 = fmaxf(r0, 0.f); r1 = fmaxf(r1, 0.f); }
    *(float2*)&out[(long)wid * NOUT + li2] = make_float2(r0, r1);
}

// ---------------- host ----------------
extern "C" void kernel_launch(void* const* d_in, const int* in_sizes, int n_in,
                              void* d_out, int out_size, void* d_ws, size_t ws_size,
                              hipStream_t stream) {
    const float* x    = (const float*)d_in[0];
    const int*   ei   = (const int*)d_in[1];
    const float* w1l  = (const float*)d_in[2];
    const float* w1r  = (const float*)d_in[3];
    const float* b1   = (const float*)d_in[4];
    const float* wxl  = (const float*)d_in[5];
    const float* wxr  = (const float*)d_in[6];
    const float* bx   = (const float*)d_in[7];
    const float* w2l  = (const float*)d_in[8];
    const float* w2r  = (const float*)d_in[9];
    const float* b2   = (const float*)d_in[10];
    const float* bn3g = (const float*)d_in[11];
    const float* bn3b = (const float*)d_in[12];
    const float* bn3m = (const float*)d_in[13];
    const float* bn3v = (const float*)d_in[14];
    const float* bn2g = (const float*)d_in[15];
    const float* bn2b = (const float*)d_in[16];
    const float* bn2m = (const float*)d_in[17];
    const float* bn2v = (const float*)d_in[18];
    float* out = (float*)d_out;

    char* p = (char*)d_ws;
    auto alloc = [&](size_t bytes) -> void* {
        void* r = (void*)p;
        p += (bytes + 255) & ~(size_t)255;
        return r;
    };
    int*   flag   = (int*)alloc(4);
    int*   cursor = (int*)alloc((size_t)NNODES * 4);
    int*   offs   = (int*)alloc((size_t)(NNODES + 1) * 4);
    int*   bsums  = (int*)alloc(128 * 4);
    int*   csr    = (int*)alloc((size_t)NEDGES * 4);
    float* bufA   = (float*)alloc((size_t)NNODES * 64 * 4); // h (layer input)
    float* bufC   = (float*)alloc((size_t)NNODES * 64 * 4); // zl
    float* bufD   = (float*)alloc((size_t)NNODES * 64 * 4); // zr
    unsigned short* B1h = (unsigned short*)alloc(16384 * 2);
    unsigned short* B1m = (unsigned short*)alloc(16384 * 2);
    unsigned short* B1l = (unsigned short*)alloc(16384 * 2);
    unsigned short* B2h = (unsigned short*)alloc(8192 * 2);
    unsigned short* B2m = (unsigned short*)alloc(8192 * 2);
    unsigned short* B2l = (unsigned short*)alloc(8192 * 2);
    unsigned short* B3h = (unsigned short*)alloc(5120 * 2);
    unsigned short* B3m = (unsigned short*)alloc(5120 * 2);
    unsigned short* B3l = (unsigned short*)alloc(5120 * 2);
    // packed edge arrays alias zl/zr scratch (dead before first gemm writes them)
    int* src32 = (int*)bufC;
    int* dst32 = (int*)bufD;

    hipMemsetAsync(cursor, 0, (size_t)NNODES * 4, stream);
    detect_kernel<<<1, 64, 0, stream>>>(ei, flag);
    prep_edges<<<2048, 256, 0, stream>>>(ei, flag, src32, dst32);
    prep_w<128, 64, 128><<<64, 256, 0, stream>>>(w1l, w1r, B1h, B1m, B1l);
    prep_w<64, 64, 128><<<32, 256, 0, stream>>>(wxl, wxr, B2h, B2m, B2l);
    prep_w<64, 40, 80><<<20, 256, 0, stream>>>(w2l, w2r, B3h, B3m, B3l);
    hist_kernel<<<2048, 256, 0, stream>>>(dst32, cursor);
    scan_bsum<<<98, 256, 0, stream>>>(cursor, bsums);
    scan_partials<<<1, 128, 0, stream>>>(bsums, 98);
    scan_write<<<98, 256, 0, stream>>>(cursor, bsums, offs);
    copy_kernel<<<391, 256, 0, stream>>>(offs, cursor);
    scatter8<<<2048, 256, 0, stream>>>(src32, dst32, cursor, csr);

    const int GB = (NNODES + 63) / 64;   // 1563
    // layer 1: x[N,128] -> h1[N,64] (relu)
    gemm_mfma<128, 64, 128><<<GB, 256, 0, stream>>>(x, B1h, B1m, B1l, b1, bufC, bufD, NNODES);
    combine_kernel<64, 0><<<25000, 256, 0, stream>>>(bufC, bufD, offs, csr,
                                                     nullptr, nullptr, nullptr, nullptr, bufA);
    // layer 2: h1 -> h2[N,64] (bn3 + relu)
    gemm_mfma<64, 64, 128><<<GB, 256, 0, stream>>>(bufA, B2h, B2m, B2l, bx, bufC, bufD, NNODES);
    combine_kernel<64, 1><<<25000, 256, 0, stream>>>(bufC, bufD, offs, csr,
                                                     bn3g, bn3b, bn3m, bn3v, bufA);
    // layer 3: h2 -> out[N,40] (bn2)
    gemm_mfma<64, 40, 80><<<GB, 256, 0, stream>>>(bufA, B3h, B3m, B3l, b2, bufC, bufD, NNODES);
    combine_kernel<40, 2><<<25000, 256, 0, stream>>>(bufC, bufD, offs, csr,
                                                     bn2g, bn2b, bn2m, bn2v, out);
}

// Round 9
// 414.122 us; speedup vs baseline: 1.0605x; 1.0605x over previous
//
#include <hip/hip_runtime.h>

#define NNODES 100000
#define NEDGES 1600000

typedef short bhalf8 __attribute__((ext_vector_type(8)));   // 8 bf16 bit patterns
typedef float f32x4 __attribute__((ext_vector_type(4)));

__device__ __forceinline__ unsigned fbits(float x){ union{float f;unsigned u;}c; c.f=x; return c.u; }
__device__ __forceinline__ float bcast(unsigned u){ union{float f;unsigned u;}c; c.u=u; return c.f; }
// round-to-nearest-even bf16 (top 16 bits of fp32)
__device__ __forceinline__ unsigned short rtn16(float x){
    unsigned u = fbits(x);
    return (unsigned short)((u + 0x7FFFu + ((u >> 16) & 1u)) >> 16);
}

// ---------------- edge dtype detect: int64 vs int32 ----------------
__global__ void detect_kernel(const int* __restrict__ ei, int* __restrict__ flag) {
    int t = threadIdx.x;                 // 0..63
    int v = ei[2 * t + 1];
    unsigned long long nz = __ballot(v != 0);
    if (t == 0) flag[0] = (nz == 0ULL) ? 1 : 0;   // 1 => int64 layout
}

// ---------------- pack edges to int32 ----------
__global__ void prep_edges(const int* __restrict__ ei, const int* __restrict__ flag,
                           int* __restrict__ src32, int* __restrict__ dst32) {
    int is64 = flag[0];
    for (int e = blockIdx.x * blockDim.x + threadIdx.x; e < NEDGES;
         e += gridDim.x * blockDim.x) {
        src32[e] = is64 ? ei[2 * e] : ei[e];
        dst32[e] = is64 ? ei[2 * (NEDGES + e)] : ei[NEDGES + e];
    }
}

// ---------------- CSR build ----------------
__global__ void hist_kernel(const int* __restrict__ dst32, int* __restrict__ deg) {
    for (int e = blockIdx.x * blockDim.x + threadIdx.x; e < NEDGES;
         e += gridDim.x * blockDim.x) {
        atomicAdd(&deg[dst32[e]], 1);
    }
}

__global__ void scan_bsum(const int* __restrict__ deg, int* __restrict__ bsums) {
    int b = blockIdx.x, t = threadIdx.x;
    long i0 = (long)b * 1024 + (long)t * 4;
    int v0 = 0, v1 = 0, v2 = 0, v3 = 0;
    if (i0 + 3 < NNODES) {
        int4 q = *(const int4*)&deg[i0];
        v0 = q.x; v1 = q.y; v2 = q.z; v3 = q.w;
    } else {
        if (i0 + 0 < NNODES) v0 = deg[i0 + 0];
        if (i0 + 1 < NNODES) v1 = deg[i0 + 1];
        if (i0 + 2 < NNODES) v2 = deg[i0 + 2];
        if (i0 + 3 < NNODES) v3 = deg[i0 + 3];
    }
    int s = v0 + v1 + v2 + v3;
    for (int off = 32; off > 0; off >>= 1) s += __shfl_down(s, off);
    __shared__ int ws[4];
    if ((t & 63) == 0) ws[t >> 6] = s;
    __syncthreads();
    if (t == 0) bsums[b] = ws[0] + ws[1] + ws[2] + ws[3];
}

__global__ void scan_partials(int* __restrict__ bsums, int nb) {
    __shared__ int sm[128];
    int t = threadIdx.x;
    int v = (t < nb) ? bsums[t] : 0;
    int run = v;
    sm[t] = run;
    __syncthreads();
    for (int off = 1; off < 128; off <<= 1) {
        int other = (t >= off) ? sm[t - off] : 0;
        __syncthreads();
        run += other;
        sm[t] = run;
        __syncthreads();
    }
    if (t < nb) bsums[t] = run - v;      // exclusive
}

__global__ void scan_write(const int* __restrict__ deg, const int* __restrict__ bsums,
                           int* __restrict__ offs) {
    int b = blockIdx.x, t = threadIdx.x;
    long i0 = (long)b * 1024 + (long)t * 4;
    int v0 = 0, v1 = 0, v2 = 0, v3 = 0;
    if (i0 + 3 < NNODES) {
        int4 q = *(const int4*)&deg[i0];
        v0 = q.x; v1 = q.y; v2 = q.z; v3 = q.w;
    } else {
        if (i0 + 0 < NNODES) v0 = deg[i0 + 0];
        if (i0 + 1 < NNODES) v1 = deg[i0 + 1];
        if (i0 + 2 < NNODES) v2 = deg[i0 + 2];
        if (i0 + 3 < NNODES) v3 = deg[i0 + 3];
    }
    int tot = v0 + v1 + v2 + v3;
    __shared__ int sm[256];
    int run = tot;
    sm[t] = run;
    __syncthreads();
    for (int off = 1; off < 256; off <<= 1) {
        int other = (t >= off) ? sm[t - off] : 0;
        __syncthreads();
        run += other;
        sm[t] = run;
        __syncthreads();
    }
    int excl = run - tot + bsums[b];
    if (i0 + 0 < NNODES) offs[i0 + 0] = excl;
    if (i0 + 1 < NNODES) offs[i0 + 1] = excl + v0;
    if (i0 + 2 < NNODES) offs[i0 + 2] = excl + v0 + v1;
    if (i0 + 3 < NNODES) offs[i0 + 3] = excl + v0 + v1 + v2;
    if (b == 0 && t == 0) offs[NNODES] = NEDGES;
}

__global__ void copy_kernel(const int* __restrict__ src, int* __restrict__ dst) {
    int i = blockIdx.x * blockDim.x + threadIdx.x;
    if (i < NNODES) dst[i] = src[i];
}

// 8 dst-range cohorts (XCD-aligned) to merge csr line writes in one L2.
__global__ void scatter8(const int* __restrict__ src32, const int* __restrict__ dst32,
                         int* __restrict__ cursor, int* __restrict__ csr) {
    const int cohort = blockIdx.x & 7;
    const int lo = cohort * 12500, hi = lo + 12500;
    const int nb = gridDim.x >> 3;
    for (int e = (blockIdx.x >> 3) * blockDim.x + threadIdx.x; e < NEDGES;
         e += nb * blockDim.x) {
        int d = dst32[e];
        if (d >= lo && d < hi) {
            int pos = atomicAdd(&cursor[d], 1);
            csr[pos] = src32[e];
        }
    }
}

// ---------------- weight prep: fp32 -> bf16 3-way split (RTN) in B-frag order
template <int K, int NL, int NTOT>
__global__ void prep_w(const float* __restrict__ wl, const float* __restrict__ wr,
                       unsigned short* __restrict__ Bh, unsigned short* __restrict__ Bm,
                       unsigned short* __restrict__ Bl) {
    constexpr int NCT = NTOT / 16;
    constexpr int TOT = (K / 32) * NCT * 512;
    for (int idx = blockIdx.x * blockDim.x + threadIdx.x; idx < TOT;
         idx += gridDim.x * blockDim.x) {
        int e = idx & 7, l = (idx >> 3) & 63, rest = idx >> 9;
        int ct = rest % NCT, kc = rest / NCT;
        int k = kc * 32 + (l >> 4) * 8 + e;
        int j = ct * 16 + (l & 15);
        float v = (j < NL) ? wl[k * NL + j] : wr[k * NL + (j - NL)];
        unsigned short h = rtn16(v);
        float r1 = v - bcast((unsigned)h << 16);    // exact
        unsigned short mdl = rtn16(r1);
        float r2 = r1 - bcast((unsigned)mdl << 16); // exact
        Bh[idx] = h;
        Bm[idx] = mdl;
        Bl[idx] = rtn16(r2);
    }
}

// ---------------- MFMA dual GEMM: Z = h @ [wl|wr], fp32-exact via 3-way split
template <int K, int NL, int NTOT>
__global__ __launch_bounds__(256) void gemm_mfma(
    const float* __restrict__ h, const unsigned short* __restrict__ Bh,
    const unsigned short* __restrict__ Bm, const unsigned short* __restrict__ Bl,
    const float* __restrict__ bias,
    float* __restrict__ zl, float* __restrict__ zr, int nrows) {
    constexpr int NCT = NTOT / 16;
    constexpr int NKC = K / 32;
    int t = threadIdx.x;
    int l = t & 63, w = t >> 6;
    int rb = blockIdx.x * 64 + w * 16;
    int arow = rb + (l & 15);
    int kg = l >> 4;
    f32x4 acc[NCT];
#pragma unroll
    for (int ct = 0; ct < NCT; ++ct) acc[ct] = (f32x4){0.f, 0.f, 0.f, 0.f};
    const bool aok = (arow < nrows);
    const float* hrow = h + (long)arow * K + kg * 8;
#pragma unroll
    for (int kc = 0; kc < NKC; ++kc) {
        float4 a0 = make_float4(0.f, 0.f, 0.f, 0.f), a1 = a0;
        if (aok) {
            a0 = *(const float4*)(hrow + kc * 32);
            a1 = *(const float4*)(hrow + kc * 32 + 4);
        }
        float av[8] = {a0.x, a0.y, a0.z, a0.w, a1.x, a1.y, a1.z, a1.w};
        bhalf8 ah, am, al;
#pragma unroll
        for (int e = 0; e < 8; ++e) {
            unsigned short hh = rtn16(av[e]);
            float r1 = av[e] - bcast((unsigned)hh << 16);
            unsigned short mm = rtn16(r1);
            float r2 = r1 - bcast((unsigned)mm << 16);
            ah[e] = (short)hh;
            am[e] = (short)mm;
            al[e] = (short)rtn16(r2);
        }
        const unsigned short* hp = Bh + (size_t)(kc * NCT) * 512 + l * 8;
        const unsigned short* mp = Bm + (size_t)(kc * NCT) * 512 + l * 8;
        const unsigned short* lp = Bl + (size_t)(kc * NCT) * 512 + l * 8;
#pragma unroll
        for (int ct = 0; ct < NCT; ++ct) {
            bhalf8 bh = *(const bhalf8*)(hp + ct * 512);
            bhalf8 bm = *(const bhalf8*)(mp + ct * 512);
            bhalf8 bl = *(const bhalf8*)(lp + ct * 512);
            acc[ct] = __builtin_amdgcn_mfma_f32_16x16x32_bf16(ah, bh, acc[ct], 0, 0, 0);
            acc[ct] = __builtin_amdgcn_mfma_f32_16x16x32_bf16(ah, bm, acc[ct], 0, 0, 0);
            acc[ct] = __builtin_amdgcn_mfma_f32_16x16x32_bf16(am, bh, acc[ct], 0, 0, 0);
            acc[ct] = __builtin_amdgcn_mfma_f32_16x16x32_bf16(ah, bl, acc[ct], 0, 0, 0);
            acc[ct] = __builtin_amdgcn_mfma_f32_16x16x32_bf16(am, bm, acc[ct], 0, 0, 0);
            acc[ct] = __builtin_amdgcn_mfma_f32_16x16x32_bf16(al, bh, acc[ct], 0, 0, 0);
        }
    }
    // D: col = l&15, row = rb + (l>>4)*4 + r   [m89-verified]
    int orow0 = rb + kg * 4;
#pragma unroll
    for (int ct = 0; ct < NCT; ++ct) {
        int j = ct * 16 + (l & 15);
        bool isl = (j < NL);
        int cc = isl ? j : j - NL;
        float bj = isl ? 0.f : bias[cc];
        float* __restrict__ dp = isl ? zl : zr;
#pragma unroll
        for (int r = 0; r < 4; ++r) {
            int orow = orow0 + r;
            if (orow < nrows) dp[(long)orow * NL + cc] = acc[ct][r] + bj;
        }
    }
}

// ---------------- aggregate + combine + epilogue ----------------
// float4 gather, CONVERGENT shfl: __shfl executed unconditionally by all 64
// lanes with clamped source lane (min(eidx, c-1)); only the ADD is masked.
// No cross-lane op ever sits under per-lane divergence.
// MODE: 0 = relu, 1 = bn+relu, 2 = bn
template <int NOUT, int MODE>
__global__ __launch_bounds__(256) void combine_kernel(
    const float* __restrict__ zl, const float* __restrict__ zr,
    const int* __restrict__ offs, const int* __restrict__ csr,
    const float* __restrict__ g, const float* __restrict__ bb,
    const float* __restrict__ m, const float* __restrict__ v,
    float* __restrict__ out) {
    int wid  = (blockIdx.x * blockDim.x + threadIdx.x) >> 6;
    int lane = threadIdx.x & 63;
    if (wid >= NNODES) return;          // wave-uniform
    int s0 = offs[wid], s1 = offs[wid + 1];
    int q   = lane >> 4;            // edge slot 0..3
    int li4 = (lane & 15) * 4;      // column group
    const bool cok = (li4 < NOUT);
    float ax = 0.f, ay = 0.f, az = 0.f, aw = 0.f;
    for (int base = s0; base < s1; base += 64) {   // uniform bounds
        int c = min(64, s1 - base);                // >= 1 here
        int cm1 = c - 1;
        int sv = (base + lane < s1) ? csr[base + lane] : 0;
        for (int p0 = 0; p0 < c; p0 += 32) {       // uniform
            float4 vv[8];
            bool okk[8];
#pragma unroll
            for (int j = 0; j < 8; ++j) {
                int eidx = p0 + 4 * j + q;
                okk[j] = (eidx < c);
                int srow = __shfl(sv, min(eidx, cm1));   // all lanes, convergent
                float4 tv = make_float4(0.f, 0.f, 0.f, 0.f);
                if (cok) tv = *(const float4*)&zl[(long)srow * NOUT + li4];
                vv[j] = tv;
            }
#pragma unroll
            for (int j = 0; j < 8; ++j) {
                if (okk[j]) { ax += vv[j].x; ay += vv[j].y; az += vv[j].z; aw += vv[j].w; }
            }
        }
    }
    // reduce across the 4 edge slots — all 64 lanes participate (convergent)
    ax += __shfl_xor(ax, 16); ay += __shfl_xor(ay, 16);
    az += __shfl_xor(az, 16); aw += __shfl_xor(aw, 16);
    ax += __shfl_xor(ax, 32); ay += __shfl_xor(ay, 32);
    az += __shfl_xor(az, 32); aw += __shfl_xor(aw, 32);
    if (q != 0 || !cok) return;
    float invd = 1.f / fmaxf((float)(s1 - s0), 1.f);
    float4 zrv = *(const float4*)&zr[(long)wid * NOUT + li4];
    float r0 = ax * invd + zrv.x;
    float r1 = ay * invd + zrv.y;
    float r2 = az * invd + zrv.z;
    float r3 = aw * invd + zrv.w;
    if (MODE == 1 || MODE == 2) {
        float4 gv = *(const float4*)&g[li4];
        float4 bv = *(const float4*)&bb[li4];
        float4 mv = *(const float4*)&m[li4];
        float4 vv = *(const float4*)&v[li4];
        r0 = (r0 - mv.x) * (gv.x * rsqrtf(vv.x + 1e-5f)) + bv.x;
        r1 = (r1 - mv.y) * (gv.y * rsqrtf(vv.y + 1e-5f)) + bv.y;
        r2 = (r2 - mv.z) * (gv.z * rsqrtf(vv.z + 1e-5f)) + bv.z;
        r3 = (r3 - mv.w) * (gv.w * rsqrtf(vv.w + 1e-5f)) + bv.w;
    }
    if (MODE == 0 || MODE == 1) {
        r0 = fmaxf(r0, 0.f); r1 = fmaxf(r1, 0.f);
        r2 = fmaxf(r2, 0.f); r3 = fmaxf(r3, 0.f);
    }
    *(float4*)&out[(long)wid * NOUT + li4] = make_float4(r0, r1, r2, r3);
}

// ---------------- host (identical to r6-passed) ----------------
extern "C" void kernel_launch(void* const* d_in, const int* in_sizes, int n_in,
                              void* d_out, int out_size, void* d_ws, size_t ws_size,
                              hipStream_t stream) {
    const float* x    = (const float*)d_in[0];
    const int*   ei   = (const int*)d_in[1];
    const float* w1l  = (const float*)d_in[2];
    const float* w1r  = (const float*)d_in[3];
    const float* b1   = (const float*)d_in[4];
    const float* wxl  = (const float*)d_in[5];
    const float* wxr  = (const float*)d_in[6];
    const float* bx   = (const float*)d_in[7];
    const float* w2l  = (const float*)d_in[8];
    const float* w2r  = (const float*)d_in[9];
    const float* b2   = (const float*)d_in[10];
    const float* bn3g = (const float*)d_in[11];
    const float* bn3b = (const float*)d_in[12];
    const float* bn3m = (const float*)d_in[13];
    const float* bn3v = (const float*)d_in[14];
    const float* bn2g = (const float*)d_in[15];
    const float* bn2b = (const float*)d_in[16];
    const float* bn2m = (const float*)d_in[17];
    const float* bn2v = (const float*)d_in[18];
    float* out = (float*)d_out;

    char* p = (char*)d_ws;
    auto alloc = [&](size_t bytes) -> void* {
        void* r = (void*)p;
        p += (bytes + 255) & ~(size_t)255;
        return r;
    };
    int*   flag   = (int*)alloc(4);
    int*   cursor = (int*)alloc((size_t)NNODES * 4);
    int*   offs   = (int*)alloc((size_t)(NNODES + 1) * 4);
    int*   bsums  = (int*)alloc(128 * 4);
    int*   csr    = (int*)alloc((size_t)NEDGES * 4);
    float* bufA   = (float*)alloc((size_t)NNODES * 64 * 4); // h (layer input)
    float* bufC   = (float*)alloc((size_t)NNODES * 64 * 4); // zl
    float* bufD   = (float*)alloc((size_t)NNODES * 64 * 4); // zr
    unsigned short* B1h = (unsigned short*)alloc(16384 * 2);
    unsigned short* B1m = (unsigned short*)alloc(16384 * 2);
    unsigned short* B1l = (unsigned short*)alloc(16384 * 2);
    unsigned short* B2h = (unsigned short*)alloc(8192 * 2);
    unsigned short* B2m = (unsigned short*)alloc(8192 * 2);
    unsigned short* B2l = (unsigned short*)alloc(8192 * 2);
    unsigned short* B3h = (unsigned short*)alloc(5120 * 2);
    unsigned short* B3m = (unsigned short*)alloc(5120 * 2);
    unsigned short* B3l = (unsigned short*)alloc(5120 * 2);
    // packed edge arrays alias zl/zr scratch (dead before first gemm writes them)
    int* src32 = (int*)bufC;
    int* dst32 = (int*)bufD;

    hipMemsetAsync(cursor, 0, (size_t)NNODES * 4, stream);
    detect_kernel<<<1, 64, 0, stream>>>(ei, flag);
    prep_edges<<<2048, 256, 0, stream>>>(ei, flag, src32, dst32);
    prep_w<128, 64, 128><<<64, 256, 0, stream>>>(w1l, w1r, B1h, B1m, B1l);
    prep_w<64, 64, 128><<<32, 256, 0, stream>>>(wxl, wxr, B2h, B2m, B2l);
    prep_w<64, 40, 80><<<20, 256, 0, stream>>>(w2l, w2r, B3h, B3m, B3l);
    hist_kernel<<<2048, 256, 0, stream>>>(dst32, cursor);
    scan_bsum<<<98, 256, 0, stream>>>(cursor, bsums);
    scan_partials<<<1, 128, 0, stream>>>(bsums, 98);
    scan_write<<<98, 256, 0, stream>>>(cursor, bsums, offs);
    copy_kernel<<<391, 256, 0, stream>>>(offs, cursor);
    scatter8<<<2048, 256, 0, stream>>>(src32, dst32, cursor, csr);

    const int GB = (NNODES + 63) / 64;   // 1563
    // layer 1: x[N,128] -> h1[N,64] (relu)
    gemm_mfma<128, 64, 128><<<GB, 256, 0, stream>>>(x, B1h, B1m, B1l, b1, bufC, bufD, NNODES);
    combine_kernel<64, 0><<<25000, 256, 0, stream>>>(bufC, bufD, offs, csr,
                                                     nullptr, nullptr, nullptr, nullptr, bufA);
    // layer 2: h1 -> h2[N,64] (bn3 + relu)
    gemm_mfma<64, 64, 128><<<GB, 256, 0, stream>>>(bufA, B2h, B2m, B2l, bx, bufC, bufD, NNODES);
    combine_kernel<64, 1><<<25000, 256, 0, stream>>>(bufC, bufD, offs, csr,
                                                     bn3g, bn3b, bn3m, bn3v, bufA);
    // layer 3: h2 -> out[N,40] (bn2)
    gemm_mfma<64, 40, 80><<<GB, 256, 0, stream>>>(bufA, B3h, B3m, B3l, b2, bufC, bufD, NNODES);
    combine_kernel<40, 2><<<25000, 256, 0, stream>>>(bufC, bufD, offs, csr,
                                                     bn2g, bn2b, bn2m, bn2v, out);
}

// Round 10
// 369.281 us; speedup vs baseline: 1.1892x; 1.1214x over previous
//
#include <hip/hip_runtime.h>

#define NNODES 100000
#define NEDGES 1600000

typedef short bhalf8 __attribute__((ext_vector_type(8)));   // 8 bf16 bit patterns
typedef float f32x4 __attribute__((ext_vector_type(4)));

__device__ __forceinline__ unsigned fbits(float x){ union{float f;unsigned u;}c; c.f=x; return c.u; }
__device__ __forceinline__ float bcast(unsigned u){ union{float f;unsigned u;}c; c.u=u; return c.f; }
// round-to-nearest-even bf16 (top 16 bits of fp32)
__device__ __forceinline__ unsigned short rtn16(float x){
    unsigned u = fbits(x);
    return (unsigned short)((u + 0x7FFFu + ((u >> 16) & 1u)) >> 16);
}
__device__ __forceinline__ float b2f(unsigned short b){ return bcast((unsigned)b << 16); }

// ---------------- edge dtype detect: int64 vs int32 ----------------
__global__ void detect_kernel(const int* __restrict__ ei, int* __restrict__ flag) {
    int t = threadIdx.x;                 // 0..63
    int v = ei[2 * t + 1];
    unsigned long long nz = __ballot(v != 0);
    if (t == 0) flag[0] = (nz == 0ULL) ? 1 : 0;   // 1 => int64 layout
}

// ---------------- pack edges to int32 + degree histogram (fused) ----------
__global__ void prep_edges(const int* __restrict__ ei, const int* __restrict__ flag,
                           int* __restrict__ src32, int* __restrict__ dst32,
                           int* __restrict__ deg) {
    int is64 = flag[0];
    for (int e = blockIdx.x * blockDim.x + threadIdx.x; e < NEDGES;
         e += gridDim.x * blockDim.x) {
        int s = is64 ? ei[2 * e] : ei[e];
        int d = is64 ? ei[2 * (NEDGES + e)] : ei[NEDGES + e];
        src32[e] = s;
        dst32[e] = d;
        atomicAdd(&deg[d], 1);
    }
}

__global__ void scan_bsum(const int* __restrict__ deg, int* __restrict__ bsums) {
    int b = blockIdx.x, t = threadIdx.x;
    long i0 = (long)b * 1024 + (long)t * 4;
    int v0 = 0, v1 = 0, v2 = 0, v3 = 0;
    if (i0 + 3 < NNODES) {
        int4 q = *(const int4*)&deg[i0];
        v0 = q.x; v1 = q.y; v2 = q.z; v3 = q.w;
    } else {
        if (i0 + 0 < NNODES) v0 = deg[i0 + 0];
        if (i0 + 1 < NNODES) v1 = deg[i0 + 1];
        if (i0 + 2 < NNODES) v2 = deg[i0 + 2];
        if (i0 + 3 < NNODES) v3 = deg[i0 + 3];
    }
    int s = v0 + v1 + v2 + v3;
    for (int off = 32; off > 0; off >>= 1) s += __shfl_down(s, off);
    __shared__ int ws[4];
    if ((t & 63) == 0) ws[t >> 6] = s;
    __syncthreads();
    if (t == 0) bsums[b] = ws[0] + ws[1] + ws[2] + ws[3];
}

__global__ void scan_partials(int* __restrict__ bsums, int nb) {
    __shared__ int sm[128];
    int t = threadIdx.x;
    int v = (t < nb) ? bsums[t] : 0;
    int run = v;
    sm[t] = run;
    __syncthreads();
    for (int off = 1; off < 128; off <<= 1) {
        int other = (t >= off) ? sm[t - off] : 0;
        __syncthreads();
        run += other;
        sm[t] = run;
        __syncthreads();
    }
    if (t < nb) bsums[t] = run - v;      // exclusive
}

// pass 3: write exclusive offsets into offs AND cursor (drops copy_kernel)
__global__ void scan_write(const int* __restrict__ deg, const int* __restrict__ bsums,
                           int* __restrict__ offs, int* __restrict__ cursor) {
    int b = blockIdx.x, t = threadIdx.x;
    long i0 = (long)b * 1024 + (long)t * 4;
    int v0 = 0, v1 = 0, v2 = 0, v3 = 0;
    if (i0 + 3 < NNODES) {
        int4 q = *(const int4*)&deg[i0];
        v0 = q.x; v1 = q.y; v2 = q.z; v3 = q.w;
    } else {
        if (i0 + 0 < NNODES) v0 = deg[i0 + 0];
        if (i0 + 1 < NNODES) v1 = deg[i0 + 1];
        if (i0 + 2 < NNODES) v2 = deg[i0 + 2];
        if (i0 + 3 < NNODES) v3 = deg[i0 + 3];
    }
    int tot = v0 + v1 + v2 + v3;
    __shared__ int sm[256];
    int run = tot;
    sm[t] = run;
    __syncthreads();
    for (int off = 1; off < 256; off <<= 1) {
        int other = (t >= off) ? sm[t - off] : 0;
        __syncthreads();
        run += other;
        sm[t] = run;
        __syncthreads();
    }
    int excl = run - tot + bsums[b];
    int o0 = excl, o1 = excl + v0, o2 = excl + v0 + v1, o3 = excl + v0 + v1 + v2;
    if (i0 + 0 < NNODES) { offs[i0 + 0] = o0; cursor[i0 + 0] = o0; }
    if (i0 + 1 < NNODES) { offs[i0 + 1] = o1; cursor[i0 + 1] = o1; }
    if (i0 + 2 < NNODES) { offs[i0 + 2] = o2; cursor[i0 + 2] = o2; }
    if (i0 + 3 < NNODES) { offs[i0 + 3] = o3; cursor[i0 + 3] = o3; }
    if (b == 0 && t == 0) offs[NNODES] = NEDGES;
}

// 8 dst-range cohorts (XCD-aligned) to merge csr line writes in one L2.
__global__ void scatter8(const int* __restrict__ src32, const int* __restrict__ dst32,
                         int* __restrict__ cursor, int* __restrict__ csr) {
    const int cohort = blockIdx.x & 7;
    const int lo = cohort * 12500, hi = lo + 12500;
    const int nb = gridDim.x >> 3;
    for (int e = (blockIdx.x >> 3) * blockDim.x + threadIdx.x; e < NEDGES;
         e += nb * blockDim.x) {
        int d = dst32[e];
        if (d >= lo && d < hi) {
            int pos = atomicAdd(&cursor[d], 1);
            csr[pos] = src32[e];
        }
    }
}

// ---------------- weight prep: fp32 -> bf16 3-way split (RTN) in B-frag order
template <int K, int NL, int NTOT>
__global__ void prep_w(const float* __restrict__ wl, const float* __restrict__ wr,
                       unsigned short* __restrict__ Bh, unsigned short* __restrict__ Bm,
                       unsigned short* __restrict__ Bl) {
    constexpr int NCT = NTOT / 16;
    constexpr int TOT = (K / 32) * NCT * 512;
    for (int idx = blockIdx.x * blockDim.x + threadIdx.x; idx < TOT;
         idx += gridDim.x * blockDim.x) {
        int e = idx & 7, l = (idx >> 3) & 63, rest = idx >> 9;
        int ct = rest % NCT, kc = rest / NCT;
        int k = kc * 32 + (l >> 4) * 8 + e;
        int j = ct * 16 + (l & 15);
        float v = (j < NL) ? wl[k * NL + j] : wr[k * NL + (j - NL)];
        unsigned short h = rtn16(v);
        float r1 = v - bcast((unsigned)h << 16);    // exact
        unsigned short mdl = rtn16(r1);
        float r2 = r1 - bcast((unsigned)mdl << 16); // exact
        Bh[idx] = h;
        Bm[idx] = mdl;
        Bl[idx] = rtn16(r2);
    }
}

// ---------------- MFMA dual GEMM: Z = h @ [wl|wr], fp32-exact via 3-way split
// zl written as bf16 (RTN) rows [nrows][NL]; zr stays fp32 (+bias).
template <int K, int NL, int NTOT>
__global__ __launch_bounds__(256) void gemm_mfma(
    const float* __restrict__ h, const unsigned short* __restrict__ Bh,
    const unsigned short* __restrict__ Bm, const unsigned short* __restrict__ Bl,
    const float* __restrict__ bias,
    unsigned short* __restrict__ zl, float* __restrict__ zr, int nrows) {
    constexpr int NCT = NTOT / 16;
    constexpr int NKC = K / 32;
    int t = threadIdx.x;
    int l = t & 63, w = t >> 6;
    int rb = blockIdx.x * 64 + w * 16;
    int arow = rb + (l & 15);
    int kg = l >> 4;
    f32x4 acc[NCT];
#pragma unroll
    for (int ct = 0; ct < NCT; ++ct) acc[ct] = (f32x4){0.f, 0.f, 0.f, 0.f};
    const bool aok = (arow < nrows);
    const float* hrow = h + (long)arow * K + kg * 8;
#pragma unroll
    for (int kc = 0; kc < NKC; ++kc) {
        float4 a0 = make_float4(0.f, 0.f, 0.f, 0.f), a1 = a0;
        if (aok) {
            a0 = *(const float4*)(hrow + kc * 32);
            a1 = *(const float4*)(hrow + kc * 32 + 4);
        }
        float av[8] = {a0.x, a0.y, a0.z, a0.w, a1.x, a1.y, a1.z, a1.w};
        bhalf8 ah, am, al;
#pragma unroll
        for (int e = 0; e < 8; ++e) {
            unsigned short hh = rtn16(av[e]);
            float r1 = av[e] - bcast((unsigned)hh << 16);
            unsigned short mm = rtn16(r1);
            float r2 = r1 - bcast((unsigned)mm << 16);
            ah[e] = (short)hh;
            am[e] = (short)mm;
            al[e] = (short)rtn16(r2);
        }
        const unsigned short* hp = Bh + (size_t)(kc * NCT) * 512 + l * 8;
        const unsigned short* mp = Bm + (size_t)(kc * NCT) * 512 + l * 8;
        const unsigned short* lp = Bl + (size_t)(kc * NCT) * 512 + l * 8;
#pragma unroll
        for (int ct = 0; ct < NCT; ++ct) {
            bhalf8 bh = *(const bhalf8*)(hp + ct * 512);
            bhalf8 bm = *(const bhalf8*)(mp + ct * 512);
            bhalf8 bl = *(const bhalf8*)(lp + ct * 512);
            acc[ct] = __builtin_amdgcn_mfma_f32_16x16x32_bf16(ah, bh, acc[ct], 0, 0, 0);
            acc[ct] = __builtin_amdgcn_mfma_f32_16x16x32_bf16(ah, bm, acc[ct], 0, 0, 0);
            acc[ct] = __builtin_amdgcn_mfma_f32_16x16x32_bf16(am, bh, acc[ct], 0, 0, 0);
            acc[ct] = __builtin_amdgcn_mfma_f32_16x16x32_bf16(ah, bl, acc[ct], 0, 0, 0);
            acc[ct] = __builtin_amdgcn_mfma_f32_16x16x32_bf16(am, bm, acc[ct], 0, 0, 0);
            acc[ct] = __builtin_amdgcn_mfma_f32_16x16x32_bf16(al, bh, acc[ct], 0, 0, 0);
        }
    }
    // D: col = l&15, row = rb + (l>>4)*4 + r   [m89-verified]
    int orow0 = rb + kg * 4;
#pragma unroll
    for (int ct = 0; ct < NCT; ++ct) {
        int j = ct * 16 + (l & 15);
        bool isl = (j < NL);
        int cc = isl ? j : j - NL;
        float bj = isl ? 0.f : bias[cc];
#pragma unroll
        for (int r = 0; r < 4; ++r) {
            int orow = orow0 + r;
            if (orow < nrows) {
                if (isl) zl[(long)orow * NL + cc] = rtn16(acc[ct][r]);
                else     zr[(long)orow * NL + cc] = acc[ct][r] + bj;
            }
        }
    }
}

// ---------------- aggregate + combine + epilogue ----------------
// bf16 zl gather (128B rows), float4-wide columns per 16-lane group, 4 edge
// slots (q); __shfl always convergent (clamped source, unconditional).
// Epilogue rows hoisted above the gather loop. MODE: 0=relu,1=bn+relu,2=bn
template <int NOUT, int MODE>
__global__ __launch_bounds__(256) void combine_kernel(
    const unsigned short* __restrict__ zl, const float* __restrict__ zr,
    const int* __restrict__ offs, const int* __restrict__ csr,
    const float* __restrict__ g, const float* __restrict__ bb,
    const float* __restrict__ m, const float* __restrict__ v,
    float* __restrict__ out) {
    int wid  = (blockIdx.x * blockDim.x + threadIdx.x) >> 6;
    int lane = threadIdx.x & 63;
    if (wid >= NNODES) return;          // wave-uniform
    int q   = lane >> 4;            // edge slot 0..3
    int li4 = (lane & 15) * 4;      // column group
    const bool cok = (li4 < NOUT);
    // hoisted epilogue loads (independent of the gather chain)
    float4 zrv = make_float4(0.f, 0.f, 0.f, 0.f);
    float4 gv = zrv, bv = zrv, mv = zrv, vv2 = zrv;
    if (cok) {
        zrv = *(const float4*)&zr[(long)wid * NOUT + li4];
        if (MODE == 1 || MODE == 2) {
            gv  = *(const float4*)&g[li4];
            bv  = *(const float4*)&bb[li4];
            mv  = *(const float4*)&m[li4];
            vv2 = *(const float4*)&v[li4];
        }
    }
    int s0 = offs[wid], s1 = offs[wid + 1];
    float ax = 0.f, ay = 0.f, az = 0.f, aw = 0.f;
    for (int base = s0; base < s1; base += 64) {   // uniform bounds
        int c = min(64, s1 - base);                // >= 1 here
        int cm1 = c - 1;
        int sv = (base + lane < s1) ? csr[base + lane] : 0;
        for (int p0 = 0; p0 < c; p0 += 32) {       // uniform
            ushort4 hv[8];
            bool okk[8];
#pragma unroll
            for (int j = 0; j < 8; ++j) {
                int eidx = p0 + 4 * j + q;
                okk[j] = (eidx < c);
                int srow = __shfl(sv, min(eidx, cm1));   // all lanes, convergent
                ushort4 tv = make_ushort4(0, 0, 0, 0);
                if (cok) tv = *(const ushort4*)&zl[(long)srow * NOUT + li4];
                hv[j] = tv;
            }
#pragma unroll
            for (int j = 0; j < 8; ++j) {
                if (okk[j]) {
                    ax += b2f(hv[j].x); ay += b2f(hv[j].y);
                    az += b2f(hv[j].z); aw += b2f(hv[j].w);
                }
            }
        }
    }
    // reduce across the 4 edge slots — all 64 lanes participate (convergent)
    ax += __shfl_xor(ax, 16); ay += __shfl_xor(ay, 16);
    az += __shfl_xor(az, 16); aw += __shfl_xor(aw, 16);
    ax += __shfl_xor(ax, 32); ay += __shfl_xor(ay, 32);
    az += __shfl_xor(az, 32); aw += __shfl_xor(aw, 32);
    if (q != 0 || !cok) return;
    float invd = 1.f / fmaxf((float)(s1 - s0), 1.f);
    float r0 = ax * invd + zrv.x;
    float r1 = ay * invd + zrv.y;
    float r2 = az * invd + zrv.z;
    float r3 = aw * invd + zrv.w;
    if (MODE == 1 || MODE == 2) {
        r0 = (r0 - mv.x) * (gv.x * rsqrtf(vv2.x + 1e-5f)) + bv.x;
        r1 = (r1 - mv.y) * (gv.y * rsqrtf(vv2.y + 1e-5f)) + bv.y;
        r2 = (r2 - mv.z) * (gv.z * rsqrtf(vv2.z + 1e-5f)) + bv.z;
        r3 = (r3 - mv.w) * (gv.w * rsqrtf(vv2.w + 1e-5f)) + bv.w;
    }
    if (MODE == 0 || MODE == 1) {
        r0 = fmaxf(r0, 0.f); r1 = fmaxf(r1, 0.f);
        r2 = fmaxf(r2, 0.f); r3 = fmaxf(r3, 0.f);
    }
    *(float4*)&out[(long)wid * NOUT + li4] = make_float4(r0, r1, r2, r3);
}

// ---------------- host ----------------
extern "C" void kernel_launch(void* const* d_in, const int* in_sizes, int n_in,
                              void* d_out, int out_size, void* d_ws, size_t ws_size,
                              hipStream_t stream) {
    const float* x    = (const float*)d_in[0];
    const int*   ei   = (const int*)d_in[1];
    const float* w1l  = (const float*)d_in[2];
    const float* w1r  = (const float*)d_in[3];
    const float* b1   = (const float*)d_in[4];
    const float* wxl  = (const float*)d_in[5];
    const float* wxr  = (const float*)d_in[6];
    const float* bx   = (const float*)d_in[7];
    const float* w2l  = (const float*)d_in[8];
    const float* w2r  = (const float*)d_in[9];
    const float* b2   = (const float*)d_in[10];
    const float* bn3g = (const float*)d_in[11];
    const float* bn3b = (const float*)d_in[12];
    const float* bn3m = (const float*)d_in[13];
    const float* bn3v = (const float*)d_in[14];
    const float* bn2g = (const float*)d_in[15];
    const float* bn2b = (const float*)d_in[16];
    const float* bn2m = (const float*)d_in[17];
    const float* bn2v = (const float*)d_in[18];
    float* out = (float*)d_out;

    char* p = (char*)d_ws;
    auto alloc = [&](size_t bytes) -> void* {
        void* r = (void*)p;
        p += (bytes + 255) & ~(size_t)255;
        return r;
    };
    int*   flag   = (int*)alloc(4);
    int*   cursor = (int*)alloc((size_t)NNODES * 4);
    int*   offs   = (int*)alloc((size_t)(NNODES + 1) * 4);
    int*   bsums  = (int*)alloc(128 * 4);
    int*   csr    = (int*)alloc((size_t)NEDGES * 4);
    float* bufA   = (float*)alloc((size_t)NNODES * 64 * 4); // h (layer input)
    unsigned short* zl16 = (unsigned short*)alloc((size_t)NNODES * 64 * 2); // bf16 zl
    float* bufD   = (float*)alloc((size_t)NNODES * 64 * 4); // zr
    unsigned short* B1h = (unsigned short*)alloc(16384 * 2);
    unsigned short* B1m = (unsigned short*)alloc(16384 * 2);
    unsigned short* B1l = (unsigned short*)alloc(16384 * 2);
    unsigned short* B2h = (unsigned short*)alloc(8192 * 2);
    unsigned short* B2m = (unsigned short*)alloc(8192 * 2);
    unsigned short* B2l = (unsigned short*)alloc(8192 * 2);
    unsigned short* B3h = (unsigned short*)alloc(5120 * 2);
    unsigned short* B3m = (unsigned short*)alloc(5120 * 2);
    unsigned short* B3l = (unsigned short*)alloc(5120 * 2);
    // packed edge arrays alias bufA/bufD (dead before first gemm/combine writes)
    int* src32 = (int*)bufA;
    int* dst32 = (int*)bufD;

    hipMemsetAsync(cursor, 0, (size_t)NNODES * 4, stream);
    detect_kernel<<<1, 64, 0, stream>>>(ei, flag);
    prep_edges<<<2048, 256, 0, stream>>>(ei, flag, src32, dst32, cursor); // + hist
    prep_w<128, 64, 128><<<64, 256, 0, stream>>>(w1l, w1r, B1h, B1m, B1l);
    prep_w<64, 64, 128><<<32, 256, 0, stream>>>(wxl, wxr, B2h, B2m, B2l);
    prep_w<64, 40, 80><<<20, 256, 0, stream>>>(w2l, w2r, B3h, B3m, B3l);
    scan_bsum<<<98, 256, 0, stream>>>(cursor, bsums);
    scan_partials<<<1, 128, 0, stream>>>(bsums, 98);
    scan_write<<<98, 256, 0, stream>>>(cursor, bsums, offs, cursor);
    scatter8<<<2048, 256, 0, stream>>>(src32, dst32, cursor, csr);

    const int GB = (NNODES + 63) / 64;   // 1563
    // layer 1: x[N,128] -> h1[N,64] (relu)   (src32 alias of bufA dead after scatter8)
    gemm_mfma<128, 64, 128><<<GB, 256, 0, stream>>>(x, B1h, B1m, B1l, b1, zl16, bufD, NNODES);
    combine_kernel<64, 0><<<25000, 256, 0, stream>>>(zl16, bufD, offs, csr,
                                                     nullptr, nullptr, nullptr, nullptr, bufA);
    // layer 2: h1 -> h2[N,64] (bn3 + relu)
    gemm_mfma<64, 64, 128><<<GB, 256, 0, stream>>>(bufA, B2h, B2m, B2l, bx, zl16, bufD, NNODES);
    combine_kernel<64, 1><<<25000, 256, 0, stream>>>(zl16, bufD, offs, csr,
                                                     bn3g, bn3b, bn3m, bn3v, bufA);
    // layer 3: h2 -> out[N,40] (bn2)
    gemm_mfma<64, 40, 80><<<GB, 256, 0, stream>>>(bufA, B3h, B3m, B3l, b2, zl16, bufD, NNODES);
    combine_kernel<40, 2><<<25000, 256, 0, stream>>>(zl16, bufD, offs, csr,
                                                     bn2g, bn2b, bn2m, bn2v, out);
}

// Round 11
// 358.185 us; speedup vs baseline: 1.2261x; 1.0310x over previous
//
#include <hip/hip_runtime.h>

#define NNODES 100000
#define NEDGES 1600000

typedef short bhalf8 __attribute__((ext_vector_type(8)));   // 8 bf16 bit patterns
typedef float f32x4 __attribute__((ext_vector_type(4)));

__device__ __forceinline__ unsigned fbits(float x){ union{float f;unsigned u;}c; c.f=x; return c.u; }
__device__ __forceinline__ float bcast(unsigned u){ union{float f;unsigned u;}c; c.u=u; return c.f; }
// round-to-nearest-even bf16 (top 16 bits of fp32)
__device__ __forceinline__ unsigned short rtn16(float x){
    unsigned u = fbits(x);
    return (unsigned short)((u + 0x7FFFu + ((u >> 16) & 1u)) >> 16);
}
__device__ __forceinline__ float b2f(unsigned short b){ return bcast((unsigned)b << 16); }

// ---------------- edge dtype detect: int64 vs int32 ----------------
__global__ void detect_kernel(const int* __restrict__ ei, int* __restrict__ flag) {
    int t = threadIdx.x;                 // 0..63
    int v = ei[2 * t + 1];
    unsigned long long nz = __ballot(v != 0);
    if (t == 0) flag[0] = (nz == 0ULL) ? 1 : 0;   // 1 => int64 layout
}

// ---------------- pack edges to int32 + degree histogram (fused) ----------
__global__ void prep_edges(const int* __restrict__ ei, const int* __restrict__ flag,
                           int* __restrict__ src32, int* __restrict__ dst32,
                           int* __restrict__ deg) {
    int is64 = flag[0];
    for (int e = blockIdx.x * blockDim.x + threadIdx.x; e < NEDGES;
         e += gridDim.x * blockDim.x) {
        int s = is64 ? ei[2 * e] : ei[e];
        int d = is64 ? ei[2 * (NEDGES + e)] : ei[NEDGES + e];
        src32[e] = s;
        dst32[e] = d;
        atomicAdd(&deg[d], 1);
    }
}

__global__ void scan_bsum(const int* __restrict__ deg, int* __restrict__ bsums) {
    int b = blockIdx.x, t = threadIdx.x;
    long i0 = (long)b * 1024 + (long)t * 4;
    int v0 = 0, v1 = 0, v2 = 0, v3 = 0;
    if (i0 + 3 < NNODES) {
        int4 q = *(const int4*)&deg[i0];
        v0 = q.x; v1 = q.y; v2 = q.z; v3 = q.w;
    } else {
        if (i0 + 0 < NNODES) v0 = deg[i0 + 0];
        if (i0 + 1 < NNODES) v1 = deg[i0 + 1];
        if (i0 + 2 < NNODES) v2 = deg[i0 + 2];
        if (i0 + 3 < NNODES) v3 = deg[i0 + 3];
    }
    int s = v0 + v1 + v2 + v3;
    for (int off = 32; off > 0; off >>= 1) s += __shfl_down(s, off);
    __shared__ int ws[4];
    if ((t & 63) == 0) ws[t >> 6] = s;
    __syncthreads();
    if (t == 0) bsums[b] = ws[0] + ws[1] + ws[2] + ws[3];
}

__global__ void scan_partials(int* __restrict__ bsums, int nb) {
    __shared__ int sm[128];
    int t = threadIdx.x;
    int v = (t < nb) ? bsums[t] : 0;
    int run = v;
    sm[t] = run;
    __syncthreads();
    for (int off = 1; off < 128; off <<= 1) {
        int other = (t >= off) ? sm[t - off] : 0;
        __syncthreads();
        run += other;
        sm[t] = run;
        __syncthreads();
    }
    if (t < nb) bsums[t] = run - v;      // exclusive
}

// pass 3: write exclusive offsets into offs AND cursor (drops copy_kernel)
__global__ void scan_write(const int* __restrict__ deg, const int* __restrict__ bsums,
                           int* __restrict__ offs, int* __restrict__ cursor) {
    int b = blockIdx.x, t = threadIdx.x;
    long i0 = (long)b * 1024 + (long)t * 4;
    int v0 = 0, v1 = 0, v2 = 0, v3 = 0;
    if (i0 + 3 < NNODES) {
        int4 q = *(const int4*)&deg[i0];
        v0 = q.x; v1 = q.y; v2 = q.z; v3 = q.w;
    } else {
        if (i0 + 0 < NNODES) v0 = deg[i0 + 0];
        if (i0 + 1 < NNODES) v1 = deg[i0 + 1];
        if (i0 + 2 < NNODES) v2 = deg[i0 + 2];
        if (i0 + 3 < NNODES) v3 = deg[i0 + 3];
    }
    int tot = v0 + v1 + v2 + v3;
    __shared__ int sm[256];
    int run = tot;
    sm[t] = run;
    __syncthreads();
    for (int off = 1; off < 256; off <<= 1) {
        int other = (t >= off) ? sm[t - off] : 0;
        __syncthreads();
        run += other;
        sm[t] = run;
        __syncthreads();
    }
    int excl = run - tot + bsums[b];
    int o0 = excl, o1 = excl + v0, o2 = excl + v0 + v1, o3 = excl + v0 + v1 + v2;
    if (i0 + 0 < NNODES) { offs[i0 + 0] = o0; cursor[i0 + 0] = o0; }
    if (i0 + 1 < NNODES) { offs[i0 + 1] = o1; cursor[i0 + 1] = o1; }
    if (i0 + 2 < NNODES) { offs[i0 + 2] = o2; cursor[i0 + 2] = o2; }
    if (i0 + 3 < NNODES) { offs[i0 + 3] = o3; cursor[i0 + 3] = o3; }
    if (b == 0 && t == 0) offs[NNODES] = NEDGES;
}

// 8 dst-range cohorts (XCD-aligned) to merge csr line writes in one L2.
// Edge streams read NON-TEMPORAL so they don't evict dirty csr lines from L2.
__global__ void scatter8(const int* __restrict__ src32, const int* __restrict__ dst32,
                         int* __restrict__ cursor, int* __restrict__ csr) {
    const int cohort = blockIdx.x & 7;
    const int lo = cohort * 12500, hi = lo + 12500;
    const int nb = gridDim.x >> 3;
    for (int e = (blockIdx.x >> 3) * blockDim.x + threadIdx.x; e < NEDGES;
         e += nb * blockDim.x) {
        int d = __builtin_nontemporal_load(&dst32[e]);
        if (d >= lo && d < hi) {
            int s = __builtin_nontemporal_load(&src32[e]);
            int pos = atomicAdd(&cursor[d], 1);
            csr[pos] = s;
        }
    }
}

// ---------------- weight prep: fp32 -> bf16 2-way split (RTN) in B-frag order
template <int K, int NL, int NTOT>
__global__ void prep_w(const float* __restrict__ wl, const float* __restrict__ wr,
                       unsigned short* __restrict__ Bh, unsigned short* __restrict__ Bl) {
    constexpr int NCT = NTOT / 16;
    constexpr int TOT = (K / 32) * NCT * 512;
    for (int idx = blockIdx.x * blockDim.x + threadIdx.x; idx < TOT;
         idx += gridDim.x * blockDim.x) {
        int e = idx & 7, l = (idx >> 3) & 63, rest = idx >> 9;
        int ct = rest % NCT, kc = rest / NCT;
        int k = kc * 32 + (l >> 4) * 8 + e;
        int j = ct * 16 + (l & 15);
        float v = (j < NL) ? wl[k * NL + j] : wr[k * NL + (j - NL)];
        unsigned short h = rtn16(v);
        float r1 = v - bcast((unsigned)h << 16);    // exact residual
        Bh[idx] = h;
        Bl[idx] = rtn16(r1);
    }
}

// ---------------- MFMA dual GEMM: Z = h @ [wl|wr], 2-way RTN split, 3 MFMA
// a = ah+al (RTN, residual <= 2^-18|a|); products hh, hl, lh; omitted ll term
// ~2^-18*sqrt(K) -- invisible under the bf16 zl rounding (2^-9).
template <int K, int NL, int NTOT>
__global__ __launch_bounds__(256) void gemm_mfma(
    const float* __restrict__ h, const unsigned short* __restrict__ Bh,
    const unsigned short* __restrict__ Bl, const float* __restrict__ bias,
    unsigned short* __restrict__ zl, float* __restrict__ zr, int nrows) {
    constexpr int NCT = NTOT / 16;
    constexpr int NKC = K / 32;
    int t = threadIdx.x;
    int l = t & 63, w = t >> 6;
    int rb = blockIdx.x * 64 + w * 16;
    int arow = rb + (l & 15);
    int kg = l >> 4;
    f32x4 acc[NCT];
#pragma unroll
    for (int ct = 0; ct < NCT; ++ct) acc[ct] = (f32x4){0.f, 0.f, 0.f, 0.f};
    const bool aok = (arow < nrows);
    const float* hrow = h + (long)arow * K + kg * 8;
#pragma unroll
    for (int kc = 0; kc < NKC; ++kc) {
        float4 a0 = make_float4(0.f, 0.f, 0.f, 0.f), a1 = a0;
        if (aok) {
            a0 = *(const float4*)(hrow + kc * 32);
            a1 = *(const float4*)(hrow + kc * 32 + 4);
        }
        float av[8] = {a0.x, a0.y, a0.z, a0.w, a1.x, a1.y, a1.z, a1.w};
        bhalf8 ah, al;
#pragma unroll
        for (int e = 0; e < 8; ++e) {
            unsigned short hh = rtn16(av[e]);
            float r1 = av[e] - bcast((unsigned)hh << 16);
            ah[e] = (short)hh;
            al[e] = (short)rtn16(r1);
        }
        const unsigned short* hp = Bh + (size_t)(kc * NCT) * 512 + l * 8;
        const unsigned short* lp = Bl + (size_t)(kc * NCT) * 512 + l * 8;
#pragma unroll
        for (int ct = 0; ct < NCT; ++ct) {
            bhalf8 bh = *(const bhalf8*)(hp + ct * 512);
            bhalf8 bl = *(const bhalf8*)(lp + ct * 512);
            acc[ct] = __builtin_amdgcn_mfma_f32_16x16x32_bf16(ah, bh, acc[ct], 0, 0, 0);
            acc[ct] = __builtin_amdgcn_mfma_f32_16x16x32_bf16(ah, bl, acc[ct], 0, 0, 0);
            acc[ct] = __builtin_amdgcn_mfma_f32_16x16x32_bf16(al, bh, acc[ct], 0, 0, 0);
        }
    }
    // D: col = l&15, row = rb + (l>>4)*4 + r   [m89-verified]
    int orow0 = rb + kg * 4;
#pragma unroll
    for (int ct = 0; ct < NCT; ++ct) {
        int j = ct * 16 + (l & 15);
        bool isl = (j < NL);
        int cc = isl ? j : j - NL;
        float bj = isl ? 0.f : bias[cc];
#pragma unroll
        for (int r = 0; r < 4; ++r) {
            int orow = orow0 + r;
            if (orow < nrows) {
                if (isl) zl[(long)orow * NL + cc] = rtn16(acc[ct][r]);
                else     zr[(long)orow * NL + cc] = acc[ct][r] + bj;
            }
        }
    }
}

// ---------------- aggregate + combine + epilogue ----------------
// bf16 zl gather (128B rows), float4-wide columns per 16-lane group, 4 edge
// slots (q); __shfl always convergent (clamped source, unconditional).
// Epilogue rows hoisted above the gather loop. MODE: 0=relu,1=bn+relu,2=bn
template <int NOUT, int MODE>
__global__ __launch_bounds__(256) void combine_kernel(
    const unsigned short* __restrict__ zl, const float* __restrict__ zr,
    const int* __restrict__ offs, const int* __restrict__ csr,
    const float* __restrict__ g, const float* __restrict__ bb,
    const float* __restrict__ m, const float* __restrict__ v,
    float* __restrict__ out) {
    int wid  = (blockIdx.x * blockDim.x + threadIdx.x) >> 6;
    int lane = threadIdx.x & 63;
    if (wid >= NNODES) return;          // wave-uniform
    int q   = lane >> 4;            // edge slot 0..3
    int li4 = (lane & 15) * 4;      // column group
    const bool cok = (li4 < NOUT);
    // hoisted epilogue loads (independent of the gather chain)
    float4 zrv = make_float4(0.f, 0.f, 0.f, 0.f);
    float4 gv = zrv, bv = zrv, mv = zrv, vv2 = zrv;
    if (cok) {
        zrv = *(const float4*)&zr[(long)wid * NOUT + li4];
        if (MODE == 1 || MODE == 2) {
            gv  = *(const float4*)&g[li4];
            bv  = *(const float4*)&bb[li4];
            mv  = *(const float4*)&m[li4];
            vv2 = *(const float4*)&v[li4];
        }
    }
    int s0 = offs[wid], s1 = offs[wid + 1];
    float ax = 0.f, ay = 0.f, az = 0.f, aw = 0.f;
    for (int base = s0; base < s1; base += 64) {   // uniform bounds
        int c = min(64, s1 - base);                // >= 1 here
        int cm1 = c - 1;
        int sv = (base + lane < s1) ? csr[base + lane] : 0;
        for (int p0 = 0; p0 < c; p0 += 32) {       // uniform
            ushort4 hv[8];
            bool okk[8];
#pragma unroll
            for (int j = 0; j < 8; ++j) {
                int eidx = p0 + 4 * j + q;
                okk[j] = (eidx < c);
                int srow = __shfl(sv, min(eidx, cm1));   // all lanes, convergent
                ushort4 tv = make_ushort4(0, 0, 0, 0);
                if (cok) tv = *(const ushort4*)&zl[(long)srow * NOUT + li4];
                hv[j] = tv;
            }
#pragma unroll
            for (int j = 0; j < 8; ++j) {
                if (okk[j]) {
                    ax += b2f(hv[j].x); ay += b2f(hv[j].y);
                    az += b2f(hv[j].z); aw += b2f(hv[j].w);
                }
            }
        }
    }
    // reduce across the 4 edge slots — all 64 lanes participate (convergent)
    ax += __shfl_xor(ax, 16); ay += __shfl_xor(ay, 16);
    az += __shfl_xor(az, 16); aw += __shfl_xor(aw, 16);
    ax += __shfl_xor(ax, 32); ay += __shfl_xor(ay, 32);
    az += __shfl_xor(az, 32); aw += __shfl_xor(aw, 32);
    if (q != 0 || !cok) return;
    float invd = 1.f / fmaxf((float)(s1 - s0), 1.f);
    float r0 = ax * invd + zrv.x;
    float r1 = ay * invd + zrv.y;
    float r2 = az * invd + zrv.z;
    float r3 = aw * invd + zrv.w;
    if (MODE == 1 || MODE == 2) {
        r0 = (r0 - mv.x) * (gv.x * rsqrtf(vv2.x + 1e-5f)) + bv.x;
        r1 = (r1 - mv.y) * (gv.y * rsqrtf(vv2.y + 1e-5f)) + bv.y;
        r2 = (r2 - mv.z) * (gv.z * rsqrtf(vv2.z + 1e-5f)) + bv.z;
        r3 = (r3 - mv.w) * (gv.w * rsqrtf(vv2.w + 1e-5f)) + bv.w;
    }
    if (MODE == 0 || MODE == 1) {
        r0 = fmaxf(r0, 0.f); r1 = fmaxf(r1, 0.f);
        r2 = fmaxf(r2, 0.f); r3 = fmaxf(r3, 0.f);
    }
    *(float4*)&out[(long)wid * NOUT + li4] = make_float4(r0, r1, r2, r3);
}

// ---------------- host ----------------
extern "C" void kernel_launch(void* const* d_in, const int* in_sizes, int n_in,
                              void* d_out, int out_size, void* d_ws, size_t ws_size,
                              hipStream_t stream) {
    const float* x    = (const float*)d_in[0];
    const int*   ei   = (const int*)d_in[1];
    const float* w1l  = (const float*)d_in[2];
    const float* w1r  = (const float*)d_in[3];
    const float* b1   = (const float*)d_in[4];
    const float* wxl  = (const float*)d_in[5];
    const float* wxr  = (const float*)d_in[6];
    const float* bx   = (const float*)d_in[7];
    const float* w2l  = (const float*)d_in[8];
    const float* w2r  = (const float*)d_in[9];
    const float* b2   = (const float*)d_in[10];
    const float* bn3g = (const float*)d_in[11];
    const float* bn3b = (const float*)d_in[12];
    const float* bn3m = (const float*)d_in[13];
    const float* bn3v = (const float*)d_in[14];
    const float* bn2g = (const float*)d_in[15];
    const float* bn2b = (const float*)d_in[16];
    const float* bn2m = (const float*)d_in[17];
    const float* bn2v = (const float*)d_in[18];
    float* out = (float*)d_out;

    char* p = (char*)d_ws;
    auto alloc = [&](size_t bytes) -> void* {
        void* r = (void*)p;
        p += (bytes + 255) & ~(size_t)255;
        return r;
    };
    int*   flag   = (int*)alloc(4);
    int*   cursor = (int*)alloc((size_t)NNODES * 4);
    int*   offs   = (int*)alloc((size_t)(NNODES + 1) * 4);
    int*   bsums  = (int*)alloc(128 * 4);
    int*   csr    = (int*)alloc((size_t)NEDGES * 4);
    float* bufA   = (float*)alloc((size_t)NNODES * 64 * 4); // h (layer input)
    unsigned short* zl16 = (unsigned short*)alloc((size_t)NNODES * 64 * 2); // bf16 zl
    float* bufD   = (float*)alloc((size_t)NNODES * 64 * 4); // zr
    unsigned short* B1h = (unsigned short*)alloc(16384 * 2);
    unsigned short* B1l = (unsigned short*)alloc(16384 * 2);
    unsigned short* B2h = (unsigned short*)alloc(8192 * 2);
    unsigned short* B2l = (unsigned short*)alloc(8192 * 2);
    unsigned short* B3h = (unsigned short*)alloc(5120 * 2);
    unsigned short* B3l = (unsigned short*)alloc(5120 * 2);
    // packed edge arrays alias bufA/bufD (dead before first gemm/combine writes)
    int* src32 = (int*)bufA;
    int* dst32 = (int*)bufD;

    hipMemsetAsync(cursor, 0, (size_t)NNODES * 4, stream);
    detect_kernel<<<1, 64, 0, stream>>>(ei, flag);
    prep_edges<<<2048, 256, 0, stream>>>(ei, flag, src32, dst32, cursor); // + hist
    prep_w<128, 64, 128><<<64, 256, 0, stream>>>(w1l, w1r, B1h, B1l);
    prep_w<64, 64, 128><<<32, 256, 0, stream>>>(wxl, wxr, B2h, B2l);
    prep_w<64, 40, 80><<<20, 256, 0, stream>>>(w2l, w2r, B3h, B3l);
    scan_bsum<<<98, 256, 0, stream>>>(cursor, bsums);
    scan_partials<<<1, 128, 0, stream>>>(bsums, 98);
    scan_write<<<98, 256, 0, stream>>>(cursor, bsums, offs, cursor);
    scatter8<<<2048, 256, 0, stream>>>(src32, dst32, cursor, csr);

    const int GB = (NNODES + 63) / 64;   // 1563
    // layer 1: x[N,128] -> h1[N,64] (relu)
    gemm_mfma<128, 64, 128><<<GB, 256, 0, stream>>>(x, B1h, B1l, b1, zl16, bufD, NNODES);
    combine_kernel<64, 0><<<25000, 256, 0, stream>>>(zl16, bufD, offs, csr,
                                                     nullptr, nullptr, nullptr, nullptr, bufA);
    // layer 2: h1 -> h2[N,64] (bn3 + relu)
    gemm_mfma<64, 64, 128><<<GB, 256, 0, stream>>>(bufA, B2h, B2l, bx, zl16, bufD, NNODES);
    combine_kernel<64, 1><<<25000, 256, 0, stream>>>(zl16, bufD, offs, csr,
                                                     bn3g, bn3b, bn3m, bn3v, bufA);
    // layer 3: h2 -> out[N,40] (bn2)
    gemm_mfma<64, 40, 80><<<GB, 256, 0, stream>>>(bufA, B3h, B3l, b2, zl16, bufD, NNODES);
    combine_kernel<40, 2><<<25000, 256, 0, stream>>>(zl16, bufD, offs, csr,
                                                     bn2g, bn2b, bn2m, bn2v, out);
}